// Round 1
// baseline (284.388 us; speedup 1.0000x reference)
//
#include <hip/hip_runtime.h>
#include <hip/hip_bf16.h>

typedef __attribute__((ext_vector_type(8))) short bf16x8;
typedef __attribute__((ext_vector_type(4))) float f32x4;

#define HD 256   // hidden size (K of the big GEMM)
#define NB 32    // batch
#define NT 4096  // timesteps
#define NE 8192  // edges per graph
#define N2 512   // 2*H (N of the big GEMM)

static __device__ __forceinline__ unsigned short f2bf(float f) {
  unsigned int u = __float_as_uint(f);
  u += 0x7fff + ((u >> 16) & 1);  // round-to-nearest-even
  return (unsigned short)(u >> 16);
}
static __device__ __forceinline__ short4 cvt4(float4 a) {
  return make_short4((short)f2bf(a.x), (short)f2bf(a.y),
                     (short)f2bf(a.z), (short)f2bf(a.w));
}
// tanh(x) = 1 - 2/(e^{2x}+1); e^{2x} via exp2. Saturates correctly at +-inf.
static __device__ __forceinline__ float fast_tanh(float x) {
  float e = __builtin_amdgcn_exp2f(x * 2.8853900817779268f);  // 2/ln2
  return __builtin_fmaf(-2.f, __builtin_amdgcn_rcpf(e + 1.f), 1.f);
}
// pack 8 fp32 (k-ascending) -> bf16x8 by truncation (validated R9)
static __device__ __forceinline__ bf16x8 pack8(float4 a, float4 b) {
  union { bf16x8 v; unsigned int u[4]; } r;
  r.u[0] = (__float_as_uint(a.y) & 0xffff0000u) | (__float_as_uint(a.x) >> 16);
  r.u[1] = (__float_as_uint(a.w) & 0xffff0000u) | (__float_as_uint(a.z) >> 16);
  r.u[2] = (__float_as_uint(b.y) & 0xffff0000u) | (__float_as_uint(b.x) >> 16);
  r.u[3] = (__float_as_uint(b.w) & 0xffff0000u) | (__float_as_uint(b.z) >> 16);
  return r.v;
}

#define GLDS16(g, l)                                                       \
  __builtin_amdgcn_global_load_lds(                                        \
      (const __attribute__((address_space(1))) unsigned int*)(g),          \
      (__attribute__((address_space(3))) unsigned int*)(l), 16, 0, 0)

// Fused prep:
//  blocks 0..255   : cvecT[n][b] = b_attn[n] + hidden[b] . W_attn[n][0:256]
//  blocks 256..383 : Wbf[n*256+k] = bf16(W_attn[n][256+k])   (one-time convert)
__global__ __launch_bounds__(256) void prep(
    const float* __restrict__ hidden, const float* __restrict__ Wattn,
    const float* __restrict__ battn, float* __restrict__ cvecT,
    short* __restrict__ Wbf) {
  const int tid = threadIdx.x;
  if (blockIdx.x < 256) {
    __shared__ float Ws[64 * 260];
    __shared__ float Hs[HD];
    const int chunk = blockIdx.x & 7;
    const int b = blockIdx.x >> 3;
#pragma unroll
    for (int it = 0; it < 16; ++it) {
      int f = it * 1024 + tid * 4;
      int i = f >> 8, k = f & 255;
      float4 w4 = *(const float4*)(Wattn + (chunk * 64 + i) * N2 + k);
      *(float4*)&Ws[i * 260 + k] = w4;
    }
    if (tid < 64)
      *(float4*)&Hs[tid * 4] = *(const float4*)(hidden + b * HD + tid * 4);
    __syncthreads();
    const int nl = tid >> 2;
    const int kb = (tid & 3) * 64;
    float sum = 0.f;
#pragma unroll
    for (int z = 0; z < 64; z += 4) {
      float4 h4 = *(const float4*)&Hs[kb + z];
      float4 w4 = *(const float4*)&Ws[nl * 260 + kb + z];
      sum = fmaf(h4.x, w4.x, sum);
      sum = fmaf(h4.y, w4.y, sum);
      sum = fmaf(h4.z, w4.z, sum);
      sum = fmaf(h4.w, w4.w, sum);
    }
    sum += __shfl_xor(sum, 1, 64);
    sum += __shfl_xor(sum, 2, 64);
    if ((tid & 3) == 0)
      cvecT[(chunk * 64 + nl) * NB + b] = sum + battn[chunk * 64 + nl];
  } else {
    int f = (blockIdx.x - 256) * 1024 + tid * 4;  // 0..131071 = n*256+k
    int n = f >> 8, k = f & 255;
    float4 w4 = *(const float4*)(Wattn + n * N2 + HD + k);
    *(short4*)(Wbf + f) = cvt4(w4);
  }
}

// Load one K-step's B fragments (8 x bf16x8) straight from global (L2-hot).
static __device__ __forceinline__ void bload(bf16x8* dst, const short* __restrict__ Wbf,
                                             int nbase, int q, int kk) {
#pragma unroll
  for (int nf = 0; nf < 8; ++nf)
    dst[nf] = *(const bf16x8*)(Wbf + (nbase + nf * 16) * HD + kk * 32 + q * 8);
}

// One K-step (BK=32): 4 A-frag reads from LDS + 32 MFMAs against held B frags.
static __device__ __forceinline__ void kstep(f32x4 acc[4][8], const float4* As4,
                                             const bf16x8* b, int m, int q, int ks) {
#pragma unroll
  for (int mi = 0; mi < 4; ++mi) {
    const int r = mi * 16 + m;
    const int cb = r * 64 + ks * 8;
    float4 a0 = As4[cb + ((2 * q) ^ (r & 7))];
    float4 a1 = As4[cb + ((2 * q + 1) ^ (r & 7))];
    bf16x8 af = pack8(a0, a1);
#pragma unroll
    for (int nf = 0; nf < 8; ++nf)
      acc[mi][nf] =
          __builtin_amdgcn_mfma_f32_16x16x32_bf16(af, b[nf], acc[mi][nf], 0, 0, 0);
  }
}

// Single-barrier GEMM: block = 64 M-rows x 512 N, 4 waves each owning 64M x 128N.
// ALL of A (64 rows x 256 K fp32 = 64 KB) is staged once via global_load_lds
// (each wave-instr stages one full 1 KB row, source chunk XOR-swizzled so LDS
// slot c of row r holds global chunk (c&~7)|((c&7)^(r&7))). B fragments are
// loaded global->VGPR per K-step (Wbf is 256 KB, L2-resident; no cross-wave
// reuse so LDS staging buys nothing), register-double-buffered one step ahead.
// The K-loop has ZERO barriers: only counted vmcnt/lgkmcnt waits remain.
__global__ __launch_bounds__(256, 2) void score_gemm(
    const float* __restrict__ enc, const short* __restrict__ Wbf,
    const float* __restrict__ cvecT, const float* __restrict__ vvec,
    float* __restrict__ scores) {
  __shared__ float4 As4[64 * 64];  // 64 rows x 64 16B-chunks = 64 KB
  __shared__ float part[4][64];
  const int tid = threadIdx.x;
  const int w = tid >> 6, lane = tid & 63, q = lane >> 4, m = lane & 15;
  const int row0 = blockIdx.x * 64;

  // ---- stage ALL of A: wave w stages row i*4+w per instruction ----
#pragma unroll
  for (int i = 0; i < 16; ++i) {
    const int r = i * 4 + w;
    const int gc = (lane & ~7) | ((lane & 7) ^ (r & 7));
    GLDS16(enc + (row0 + r) * HD + gc * 4, &As4[r * 64]);
  }

  f32x4 acc[4][8];
#pragma unroll
  for (int mi = 0; mi < 4; ++mi)
#pragma unroll
    for (int nf = 0; nf < 8; ++nf) acc[mi][nf] = (f32x4){0.f, 0.f, 0.f, 0.f};

  const int nbase = w * 128 + m;
  bf16x8 b0[8], b1[8];
  bload(b0, Wbf, nbase, q, 0);  // prologue B (drained by the barrier, harmless)

  __syncthreads();  // the ONLY barrier: A staged, everyone may read LDS

#pragma unroll 1
  for (int ks2 = 0; ks2 < 4; ++ks2) {
    const int ks = ks2 * 2;
    bload(b1, Wbf, nbase, q, ks + 1);   // prefetch next step's B
    kstep(acc, As4, b0, m, q, ks);
    if (ks2 < 3) bload(b0, Wbf, nbase, q, ks + 2);
    kstep(acc, As4, b1, m, q, ks + 1);
  }

  // ---- epilogue: tanh + v-dot, reduce over this wave's 128 cols ----
  float p[4][4];
#pragma unroll
  for (int mi = 0; mi < 4; ++mi)
#pragma unroll
    for (int j = 0; j < 4; ++j) p[mi][j] = 0.f;

#pragma unroll
  for (int nf = 0; nf < 8; ++nf) {
    const int n = w * 128 + nf * 16 + m;
    const float vv = vvec[n];
    // C/D layout: M-coord = mi*16 + 4q+j, N-coord = n; b = M & 31
    const f32x4 cvA = *(const f32x4*)(cvecT + n * NB + 4 * q);        // mi even
    const f32x4 cvB = *(const f32x4*)(cvecT + n * NB + 16 + 4 * q);   // mi odd
#pragma unroll
    for (int mi = 0; mi < 4; ++mi) {
      const f32x4 cv = (mi & 1) ? cvB : cvA;
#pragma unroll
      for (int j = 0; j < 4; ++j)
        p[mi][j] += fast_tanh(acc[mi][nf][j] + cv[j]) * vv;
    }
  }
#pragma unroll
  for (int mi = 0; mi < 4; ++mi) {
#pragma unroll
    for (int j = 0; j < 4; ++j) {
      float e = p[mi][j];
      e += __shfl_xor(e, 1, 64);
      e += __shfl_xor(e, 2, 64);
      e += __shfl_xor(e, 4, 64);
      e += __shfl_xor(e, 8, 64);  // sum over the 16 m-lanes
      if (m == 0) part[w][mi * 16 + 4 * q + j] = e;
    }
  }
  __syncthreads();
  if (tid < 64) {
    const int r = row0 + tid;  // flat row = t*NB + b
    scores[(r & 31) * NT + (r >> 5)] =
        part[0][tid] + part[1][tid] + part[2][tid] + part[3][tid];
  }
}

// Fused softmax + edge scatter: one block per batch b (1024 threads).
// Softmax weights (0.1*softmax) AND the output accumulator live in LDS;
// edges do LDS atomics (ds_add_f32) instead of 262K device-scope L2 atomics;
// out is written once, coalesced (no separate zeroing pass).
__global__ __launch_bounds__(1024) void softmax_scatter(
    const float* __restrict__ sc, const int* __restrict__ esrc,
    const int* __restrict__ edst, float* __restrict__ out) {
  __shared__ float wls[NT];   // 16 KB: 0.1 * softmax(sc[b])
  __shared__ float accs[NT];  // 16 KB: scatter accumulator
  __shared__ float rtmp[16];
  __shared__ float rmax, rinv;
  const int b = blockIdx.x;
  const int tid = threadIdx.x;
  const int wid = tid >> 6, lane = tid & 63;

  float s[4];
  float mx = -1e30f;
#pragma unroll
  for (int p = 0; p < 4; ++p) {
    s[p] = sc[b * NT + tid + p * 1024];
    mx = fmaxf(mx, s[p]);
  }
#pragma unroll
  for (int d = 32; d >= 1; d >>= 1) mx = fmaxf(mx, __shfl_xor(mx, d, 64));
  if (lane == 0) rtmp[wid] = mx;
  __syncthreads();
  if (tid == 0) {
    float mm = rtmp[0];
#pragma unroll
    for (int i = 1; i < 16; ++i) mm = fmaxf(mm, rtmp[i]);
    rmax = mm;
  }
  __syncthreads();
  mx = rmax;
  float e[4];
  float sm = 0.f;
#pragma unroll
  for (int p = 0; p < 4; ++p) {
    e[p] = __expf(s[p] - mx);
    sm += e[p];
  }
#pragma unroll
  for (int d = 32; d >= 1; d >>= 1) sm += __shfl_xor(sm, d, 64);
  if (lane == 0) rtmp[wid] = sm;
  __syncthreads();
  if (tid == 0) {
    float tt = 0.f;
#pragma unroll
    for (int i = 0; i < 16; ++i) tt += rtmp[i];
    rinv = 0.1f / tt;
  }
  __syncthreads();
  const float inv = rinv;
#pragma unroll
  for (int p = 0; p < 4; ++p) {
    wls[tid + p * 1024] = e[p] * inv;
    accs[tid + p * 1024] = 0.f;
  }
  __syncthreads();
#pragma unroll
  for (int i = 0; i < 8; ++i) {
    const int eid = b * NE + tid + i * 1024;
    const int ss = esrc[eid];
    const int dd = edst[eid];
    const float wv = wls[ss];
    if (dd != ss + 1) atomicAdd(&accs[dd], wv);
  }
  __syncthreads();
#pragma unroll
  for (int p = 0; p < 4; ++p)
    out[b * NT + tid + p * 1024] = accs[tid + p * 1024];
}

extern "C" void kernel_launch(void* const* d_in, const int* in_sizes, int n_in,
                              void* d_out, int out_size, void* d_ws, size_t ws_size,
                              hipStream_t stream) {
  const float* hidden = (const float*)d_in[0];
  const float* enc    = (const float*)d_in[1];
  const int*   esrc   = (const int*)d_in[2];
  const int*   edst   = (const int*)d_in[3];
  const float* Wattn  = (const float*)d_in[4];
  const float* battn  = (const float*)d_in[5];
  const float* vvec   = (const float*)d_in[6];
  float* out = (float*)d_out;

  char* ws = (char*)d_ws;
  float* cvecT  = (float*)ws;                    // 512*32*4   = 64 KB
  short* Wbf    = (short*)(ws + 65536);          // 512*256*2  = 256 KB
  float* scores = (float*)(ws + 65536 + 262144); // 32*4096*4  = 512 KB

  prep<<<384, 256, 0, stream>>>(hidden, Wattn, battn, cvecT, Wbf);
  score_gemm<<<(NB * NT) / 64, 256, 0, stream>>>(enc, Wbf, cvecT, vvec, scores);
  softmax_scatter<<<NB, 1024, 0, stream>>>(scores, esrc, edst, out);
}

// Round 2
// 279.167 us; speedup vs baseline: 1.0187x; 1.0187x over previous
//
#include <hip/hip_runtime.h>
#include <hip/hip_bf16.h>

typedef __attribute__((ext_vector_type(8))) short bf16x8;
typedef __attribute__((ext_vector_type(4))) float f32x4;

#define HD 256   // hidden size (K of the big GEMM)
#define NB 32    // batch
#define NT 4096  // timesteps
#define NE 8192  // edges per graph
#define N2 512   // 2*H (N of the big GEMM)

static __device__ __forceinline__ unsigned short f2bf(float f) {
  unsigned int u = __float_as_uint(f);
  u += 0x7fff + ((u >> 16) & 1);  // round-to-nearest-even
  return (unsigned short)(u >> 16);
}
static __device__ __forceinline__ short4 cvt4(float4 a) {
  return make_short4((short)f2bf(a.x), (short)f2bf(a.y),
                     (short)f2bf(a.z), (short)f2bf(a.w));
}
// tanh(x) = 1 - 2/(e^{2x}+1); e^{2x} via exp2. Saturates correctly at +-inf.
static __device__ __forceinline__ float fast_tanh(float x) {
  float e = __builtin_amdgcn_exp2f(x * 2.8853900817779268f);  // 2/ln2
  return __builtin_fmaf(-2.f, __builtin_amdgcn_rcpf(e + 1.f), 1.f);
}
// pack 8 fp32 (k-ascending) -> bf16x8 by truncation (validated R9)
static __device__ __forceinline__ bf16x8 pack8(float4 a, float4 b) {
  union { bf16x8 v; unsigned int u[4]; } r;
  r.u[0] = (__float_as_uint(a.y) & 0xffff0000u) | (__float_as_uint(a.x) >> 16);
  r.u[1] = (__float_as_uint(a.w) & 0xffff0000u) | (__float_as_uint(a.z) >> 16);
  r.u[2] = (__float_as_uint(b.y) & 0xffff0000u) | (__float_as_uint(b.x) >> 16);
  r.u[3] = (__float_as_uint(b.w) & 0xffff0000u) | (__float_as_uint(b.z) >> 16);
  return r.v;
}

// Fused prep:
//  blocks 0..255   : cvecT[n][b] = b_attn[n] + hidden[b] . W_attn[n][0:256]
//  blocks 256..383 : Wbf[n*256+k] = bf16(W_attn[n][256+k])   (one-time convert)
__global__ __launch_bounds__(256) void prep(
    const float* __restrict__ hidden, const float* __restrict__ Wattn,
    const float* __restrict__ battn, float* __restrict__ cvecT,
    short* __restrict__ Wbf) {
  const int tid = threadIdx.x;
  if (blockIdx.x < 256) {
    __shared__ float Ws[64 * 260];
    __shared__ float Hs[HD];
    const int chunk = blockIdx.x & 7;
    const int b = blockIdx.x >> 3;
#pragma unroll
    for (int it = 0; it < 16; ++it) {
      int f = it * 1024 + tid * 4;
      int i = f >> 8, k = f & 255;
      float4 w4 = *(const float4*)(Wattn + (chunk * 64 + i) * N2 + k);
      *(float4*)&Ws[i * 260 + k] = w4;
    }
    if (tid < 64)
      *(float4*)&Hs[tid * 4] = *(const float4*)(hidden + b * HD + tid * 4);
    __syncthreads();
    const int nl = tid >> 2;
    const int kb = (tid & 3) * 64;
    float sum = 0.f;
#pragma unroll
    for (int z = 0; z < 64; z += 4) {
      float4 h4 = *(const float4*)&Hs[kb + z];
      float4 w4 = *(const float4*)&Ws[nl * 260 + kb + z];
      sum = fmaf(h4.x, w4.x, sum);
      sum = fmaf(h4.y, w4.y, sum);
      sum = fmaf(h4.z, w4.z, sum);
      sum = fmaf(h4.w, w4.w, sum);
    }
    sum += __shfl_xor(sum, 1, 64);
    sum += __shfl_xor(sum, 2, 64);
    if ((tid & 3) == 0)
      cvecT[(chunk * 64 + nl) * NB + b] = sum + battn[chunk * 64 + nl];
  } else {
    int f = (blockIdx.x - 256) * 1024 + tid * 4;  // 0..131071 = n*256+k
    int n = f >> 8, k = f & 255;
    float4 w4 = *(const float4*)(Wattn + n * N2 + HD + k);
    *(short4*)(Wbf + f) = cvt4(w4);
  }
}

// Load one K-step's B fragments (4 x bf16x8) straight from global (L2-hot).
static __device__ __forceinline__ void bload(bf16x8* dst, const short* __restrict__ Wbf,
                                             int nbase, int q, int kk) {
#pragma unroll
  for (int nf = 0; nf < 4; ++nf)
    dst[nf] = *(const bf16x8*)(Wbf + (nbase + nf * 16) * HD + kk * 32 + q * 8);
}

// One K-step (BK=32): 4 A-frag bf16 ds_reads + 16 MFMAs against held B frags.
static __device__ __forceinline__ void kstep(f32x4 acc[4][4], const short* Abf,
                                             const bf16x8* b, int m, int q, int ks) {
#pragma unroll
  for (int mi = 0; mi < 4; ++mi) {
    const int r = mi * 16 + m;
    const int cc = ks * 4 + q;
    const int slot = (cc & ~7) | ((cc & 7) ^ (r & 7));
    bf16x8 af = *(const bf16x8*)&Abf[r * 256 + slot * 8];
#pragma unroll
    for (int nf = 0; nf < 4; ++nf)
      acc[mi][nf] =
          __builtin_amdgcn_mfma_f32_16x16x32_bf16(af, b[nf], acc[mi][nf], 0, 0, 0);
  }
}

// Occupancy-first GEMM: block = 512 threads (8 waves), 64 M-rows x 512 N.
// Wave w owns 64M x 64N (cols w*64..w*64+63): acc[4][4] f32x4 = 64 acc regs,
// so total regs fit under the 128-reg cliff -> 16 waves/CU (2 blocks/CU),
// double the old occupancy. A is reg-staged fp32->bf16 into LDS ONCE
// (32 KB, XOR-swizzled 16B chunks: chunk c of row r at slot (c&~7)|((c&7)^(r&7))),
// removing pack8 from the K-loop; A-frags are direct ds_read_b128.
// B fragments stream global->VGPR (Wbf 256 KB, L2-resident), reg-double-buffered.
// Single __syncthreads for the whole kernel; K-loop is barrier-free.
__global__ __launch_bounds__(512, 4) void score_gemm(
    const float* __restrict__ enc, const short* __restrict__ Wbf,
    const float* __restrict__ cvecT, const float* __restrict__ vvec,
    float* __restrict__ scores) {
  __shared__ short Abf[64 * 256];  // 64 rows x 256 k bf16, swizzled: 32 KB
  __shared__ float part[8][64];
  const int tid = threadIdx.x;
  const int w = tid >> 6, lane = tid & 63, q = lane >> 4, m = lane & 15;
  const int row0 = blockIdx.x * 64;

  // ---- stage ALL of A: fp32 global -> bf16 LDS (each thread 4 chunks) ----
#pragma unroll
  for (int i = 0; i < 4; ++i) {
    const int g = i * 512 + tid;      // 0..2047 = r*32 + c
    const int r = g >> 5, c = g & 31; // chunk c covers k = c*8..c*8+7
    const float* src = enc + (row0 + r) * HD + c * 8;
    float4 a0 = *(const float4*)src;
    float4 a1 = *(const float4*)(src + 4);
    const int slot = (c & ~7) | ((c & 7) ^ (r & 7));
    *(bf16x8*)&Abf[r * 256 + slot * 8] = pack8(a0, a1);
  }

  f32x4 acc[4][4];
#pragma unroll
  for (int mi = 0; mi < 4; ++mi)
#pragma unroll
    for (int nf = 0; nf < 4; ++nf) acc[mi][nf] = (f32x4){0.f, 0.f, 0.f, 0.f};

  const int nbase = w * 64 + m;
  bf16x8 b0[4], b1[4];
  bload(b0, Wbf, nbase, q, 0);  // prologue B prefetch

  __syncthreads();  // the ONLY barrier: A staged, everyone may read LDS

#pragma unroll 1
  for (int ks2 = 0; ks2 < 4; ++ks2) {
    const int ks = ks2 * 2;
    bload(b1, Wbf, nbase, q, ks + 1);   // prefetch next step's B
    kstep(acc, Abf, b0, m, q, ks);
    if (ks2 < 3) bload(b0, Wbf, nbase, q, ks + 2);
    kstep(acc, Abf, b1, m, q, ks + 1);
  }

  // ---- epilogue: tanh + v-dot, reduce over this wave's 64 cols ----
  float p[4][4];
#pragma unroll
  for (int mi = 0; mi < 4; ++mi)
#pragma unroll
    for (int j = 0; j < 4; ++j) p[mi][j] = 0.f;

#pragma unroll
  for (int nf = 0; nf < 4; ++nf) {
    const int n = w * 64 + nf * 16 + m;
    const float vv = vvec[n];
    // C/D layout: M-coord = mi*16 + 4q+j, N-coord = n; b = M & 31
    const f32x4 cvA = *(const f32x4*)(cvecT + n * NB + 4 * q);        // mi even
    const f32x4 cvB = *(const f32x4*)(cvecT + n * NB + 16 + 4 * q);   // mi odd
#pragma unroll
    for (int mi = 0; mi < 4; ++mi) {
      const f32x4 cv = (mi & 1) ? cvB : cvA;
#pragma unroll
      for (int j = 0; j < 4; ++j)
        p[mi][j] += fast_tanh(acc[mi][nf][j] + cv[j]) * vv;
    }
  }
#pragma unroll
  for (int mi = 0; mi < 4; ++mi) {
#pragma unroll
    for (int j = 0; j < 4; ++j) {
      float e = p[mi][j];
      e += __shfl_xor(e, 1, 64);
      e += __shfl_xor(e, 2, 64);
      e += __shfl_xor(e, 4, 64);
      e += __shfl_xor(e, 8, 64);  // sum over the 16 m-lanes
      if (m == 0) part[w][mi * 16 + 4 * q + j] = e;
    }
  }
  __syncthreads();
  if (tid < 64) {
    const int r = row0 + tid;  // flat row = t*NB + b
    float s = 0.f;
#pragma unroll
    for (int ww = 0; ww < 8; ++ww) s += part[ww][tid];
    scores[(r & 31) * NT + (r >> 5)] = s;
  }
}

// Fused softmax + edge scatter: one block per batch b (1024 threads).
// Softmax weights (0.1*softmax) AND the output accumulator live in LDS;
// edges do LDS atomics (ds_add_f32) instead of 262K device-scope L2 atomics;
// out is written once, coalesced (no separate zeroing pass).
__global__ __launch_bounds__(1024) void softmax_scatter(
    const float* __restrict__ sc, const int* __restrict__ esrc,
    const int* __restrict__ edst, float* __restrict__ out) {
  __shared__ float wls[NT];   // 16 KB: 0.1 * softmax(sc[b])
  __shared__ float accs[NT];  // 16 KB: scatter accumulator
  __shared__ float rtmp[16];
  __shared__ float rmax, rinv;
  const int b = blockIdx.x;
  const int tid = threadIdx.x;
  const int wid = tid >> 6, lane = tid & 63;

  float s[4];
  float mx = -1e30f;
#pragma unroll
  for (int p = 0; p < 4; ++p) {
    s[p] = sc[b * NT + tid + p * 1024];
    mx = fmaxf(mx, s[p]);
  }
#pragma unroll
  for (int d = 32; d >= 1; d >>= 1) mx = fmaxf(mx, __shfl_xor(mx, d, 64));
  if (lane == 0) rtmp[wid] = mx;
  __syncthreads();
  if (tid == 0) {
    float mm = rtmp[0];
#pragma unroll
    for (int i = 1; i < 16; ++i) mm = fmaxf(mm, rtmp[i]);
    rmax = mm;
  }
  __syncthreads();
  mx = rmax;
  float e[4];
  float sm = 0.f;
#pragma unroll
  for (int p = 0; p < 4; ++p) {
    e[p] = __expf(s[p] - mx);
    sm += e[p];
  }
#pragma unroll
  for (int d = 32; d >= 1; d >>= 1) sm += __shfl_xor(sm, d, 64);
  if (lane == 0) rtmp[wid] = sm;
  __syncthreads();
  if (tid == 0) {
    float tt = 0.f;
#pragma unroll
    for (int i = 0; i < 16; ++i) tt += rtmp[i];
    rinv = 0.1f / tt;
  }
  __syncthreads();
  const float inv = rinv;
#pragma unroll
  for (int p = 0; p < 4; ++p) {
    wls[tid + p * 1024] = e[p] * inv;
    accs[tid + p * 1024] = 0.f;
  }
  __syncthreads();
#pragma unroll
  for (int i = 0; i < 8; ++i) {
    const int eid = b * NE + tid + i * 1024;
    const int ss = esrc[eid];
    const int dd = edst[eid];
    const float wv = wls[ss];
    if (dd != ss + 1) atomicAdd(&accs[dd], wv);
  }
  __syncthreads();
#pragma unroll
  for (int p = 0; p < 4; ++p)
    out[b * NT + tid + p * 1024] = accs[tid + p * 1024];
}

extern "C" void kernel_launch(void* const* d_in, const int* in_sizes, int n_in,
                              void* d_out, int out_size, void* d_ws, size_t ws_size,
                              hipStream_t stream) {
  const float* hidden = (const float*)d_in[0];
  const float* enc    = (const float*)d_in[1];
  const int*   esrc   = (const int*)d_in[2];
  const int*   edst   = (const int*)d_in[3];
  const float* Wattn  = (const float*)d_in[4];
  const float* battn  = (const float*)d_in[5];
  const float* vvec   = (const float*)d_in[6];
  float* out = (float*)d_out;

  char* ws = (char*)d_ws;
  float* cvecT  = (float*)ws;                    // 512*32*4   = 64 KB
  short* Wbf    = (short*)(ws + 65536);          // 512*256*2  = 256 KB
  float* scores = (float*)(ws + 65536 + 262144); // 32*4096*4  = 512 KB

  prep<<<384, 256, 0, stream>>>(hidden, Wattn, battn, cvecT, Wbf);
  score_gemm<<<(NB * NT) / 64, 512, 0, stream>>>(enc, Wbf, cvecT, vvec, scores);
  softmax_scatter<<<NB, 1024, 0, stream>>>(scores, esrc, edst, out);
}

// Round 3
// 274.507 us; speedup vs baseline: 1.0360x; 1.0170x over previous
//
#include <hip/hip_runtime.h>
#include <hip/hip_bf16.h>

typedef __attribute__((ext_vector_type(8))) short bf16x8;
typedef __attribute__((ext_vector_type(4))) float f32x4;

#define HD 256   // hidden size (K of the big GEMM)
#define NB 32    // batch
#define NT 4096  // timesteps
#define NE 8192  // edges per graph
#define N2 512   // 2*H (N of the big GEMM)

static __device__ __forceinline__ unsigned short f2bf(float f) {
  unsigned int u = __float_as_uint(f);
  u += 0x7fff + ((u >> 16) & 1);  // round-to-nearest-even
  return (unsigned short)(u >> 16);
}
static __device__ __forceinline__ short4 cvt4(float4 a) {
  return make_short4((short)f2bf(a.x), (short)f2bf(a.y),
                     (short)f2bf(a.z), (short)f2bf(a.w));
}
// tanh(x) = 1 - 2/(e^{2x}+1); e^{2x} via exp2. Saturates correctly at +-inf.
static __device__ __forceinline__ float fast_tanh(float x) {
  float e = __builtin_amdgcn_exp2f(x * 2.8853900817779268f);  // 2/ln2
  return __builtin_fmaf(-2.f, __builtin_amdgcn_rcpf(e + 1.f), 1.f);
}
// pack 8 fp32 (k-ascending) -> bf16x8 by truncation (validated R9)
static __device__ __forceinline__ bf16x8 pack8(float4 a, float4 b) {
  union { bf16x8 v; unsigned int u[4]; } r;
  r.u[0] = (__float_as_uint(a.y) & 0xffff0000u) | (__float_as_uint(a.x) >> 16);
  r.u[1] = (__float_as_uint(a.w) & 0xffff0000u) | (__float_as_uint(a.z) >> 16);
  r.u[2] = (__float_as_uint(b.y) & 0xffff0000u) | (__float_as_uint(b.x) >> 16);
  r.u[3] = (__float_as_uint(b.w) & 0xffff0000u) | (__float_as_uint(b.z) >> 16);
  return r.v;
}

// Fused prep:
//  blocks 0..255   : cvecT[n][b] = b_attn[n] + hidden[b] . W_attn[n][0:256]
//  blocks 256..383 : WbfT k-block-major bf16 convert of W_attn[n][256+k]:
//                    WbfT[((k>>5)*512 + n)*32 + (k&31)] = bf16(W2[n][k])
//                    -> a gemm wave's 4 B-frag loads are each 1KB CONTIGUOUS.
__global__ __launch_bounds__(256) void prep(
    const float* __restrict__ hidden, const float* __restrict__ Wattn,
    const float* __restrict__ battn, float* __restrict__ cvecT,
    short* __restrict__ WbfT) {
  const int tid = threadIdx.x;
  if (blockIdx.x < 256) {
    __shared__ float Ws[64 * 260];
    __shared__ float Hs[HD];
    const int chunk = blockIdx.x & 7;
    const int b = blockIdx.x >> 3;
#pragma unroll
    for (int it = 0; it < 16; ++it) {
      int f = it * 1024 + tid * 4;
      int i = f >> 8, k = f & 255;
      float4 w4 = *(const float4*)(Wattn + (chunk * 64 + i) * N2 + k);
      *(float4*)&Ws[i * 260 + k] = w4;
    }
    if (tid < 64)
      *(float4*)&Hs[tid * 4] = *(const float4*)(hidden + b * HD + tid * 4);
    __syncthreads();
    const int nl = tid >> 2;
    const int kb = (tid & 3) * 64;
    float sum = 0.f;
#pragma unroll
    for (int z = 0; z < 64; z += 4) {
      float4 h4 = *(const float4*)&Hs[kb + z];
      float4 w4 = *(const float4*)&Ws[nl * 260 + kb + z];
      sum = fmaf(h4.x, w4.x, sum);
      sum = fmaf(h4.y, w4.y, sum);
      sum = fmaf(h4.z, w4.z, sum);
      sum = fmaf(h4.w, w4.w, sum);
    }
    sum += __shfl_xor(sum, 1, 64);
    sum += __shfl_xor(sum, 2, 64);
    if ((tid & 3) == 0)
      cvecT[(chunk * 64 + nl) * NB + b] = sum + battn[chunk * 64 + nl];
  } else {
    int f = (blockIdx.x - 256) * 1024 + tid * 4;  // 0..131071 = n*256+k
    int n = f >> 8, k = f & 255;                  // k multiple of 4
    float4 w4 = *(const float4*)(Wattn + n * N2 + HD + k);
    *(short4*)(WbfT + ((k >> 5) * 512 + n) * 32 + (k & 31)) = cvt4(w4);
  }
}

// Load one K-step's B fragments (4 x bf16x8). Coalesced: for fixed (kk,nf)
// the wave's 64 lanes (q=lane>>4, m=lane&15) cover one CONTIGUOUS 1KB run
// of WbfT: addr = ((kk*512 + nbase+nf*16+m)*32 + q*8)*2 bytes.
static __device__ __forceinline__ void bload(bf16x8* dst, const short* __restrict__ Wp,
                                             int nbase, int q, int kk) {
  const short* base = Wp + (kk * 512 + nbase) * 32 + q * 8;
#pragma unroll
  for (int nf = 0; nf < 4; ++nf)
    dst[nf] = *(const bf16x8*)(base + nf * 16 * 32);
}

// One K-step (BK=32): 4 A-frag bf16 ds_reads + 16 MFMAs against held B frags.
// rb = this wave's M-group row base (0 or 64).
static __device__ __forceinline__ void kstep(f32x4 acc[4][4], const short* Abf,
                                             const bf16x8* b, int rb, int m, int q,
                                             int ks) {
#pragma unroll
  for (int mi = 0; mi < 4; ++mi) {
    const int r = rb + mi * 16 + m;
    const int cc = ks * 4 + q;
    const int slot = (cc & ~7) | ((cc & 7) ^ (r & 7));
    bf16x8 af = *(const bf16x8*)&Abf[r * 256 + slot * 8];
#pragma unroll
    for (int nf = 0; nf < 4; ++nf)
      acc[mi][nf] =
          __builtin_amdgcn_mfma_f32_16x16x32_bf16(af, b[nf], acc[mi][nf], 0, 0, 0);
  }
}

// B-coalesced, M128 GEMM: block = 1024 threads (16 waves), 128 M-rows x 512 N.
// Two 8-wave M-groups (g = w>>3): group g owns rows g*64..g*64+63; wave wl=w&7
// owns cols wl*64..wl*64+63 -> acc[4][4] f32x4 per wave (same regs as R2).
// B addresses are independent of g, so group 1's B-frag loads hit L1 behind
// group 0's -> block reads 256KB of B for 128 rows (half of R2's rate), and
// each B wave-load is 1KB contiguous (8 full lines vs 16 partial before):
// ~4.7x fewer L1 line transactions on the B stream, the presumed serializer.
// A staged once fp32->bf16 into 64KB LDS (XOR-swizzled); K-loop barrier-free.
__global__ __launch_bounds__(1024, 4) void score_gemm(
    const float* __restrict__ enc, const short* __restrict__ WbfT,
    const float* __restrict__ cvecT, const float* __restrict__ vvec,
    float* __restrict__ scores) {
  __shared__ short Abf[128 * 256];  // 128 rows x 256 k bf16, swizzled: 64 KB
  __shared__ float part[16][64];
  const int tid = threadIdx.x;
  const int w = tid >> 6, lane = tid & 63, q = lane >> 4, m = lane & 15;
  const int g = w >> 3, wl = w & 7;
  const int row0 = blockIdx.x * 128;

  // ---- stage ALL of A: fp32 global -> bf16 LDS (each thread 4 chunks) ----
#pragma unroll
  for (int i = 0; i < 4; ++i) {
    const int gg = i * 1024 + tid;     // 0..4095 = r*32 + c
    const int r = gg >> 5, c = gg & 31;
    const float* src = enc + (row0 + r) * HD + c * 8;
    float4 a0 = *(const float4*)src;
    float4 a1 = *(const float4*)(src + 4);
    const int slot = (c & ~7) | ((c & 7) ^ (r & 7));
    *(bf16x8*)&Abf[r * 256 + slot * 8] = pack8(a0, a1);
  }

  f32x4 acc[4][4];
#pragma unroll
  for (int mi = 0; mi < 4; ++mi)
#pragma unroll
    for (int nf = 0; nf < 4; ++nf) acc[mi][nf] = (f32x4){0.f, 0.f, 0.f, 0.f};

  const int nbase = wl * 64 + m;
  const int rb = g * 64;
  bf16x8 b0[4], b1[4];
  bload(b0, WbfT, nbase, q, 0);  // prologue B prefetch

  __syncthreads();  // the ONLY barrier: A staged, everyone may read LDS

#pragma unroll 1
  for (int ks2 = 0; ks2 < 4; ++ks2) {
    const int ks = ks2 * 2;
    bload(b1, WbfT, nbase, q, ks + 1);  // prefetch next step's B
    kstep(acc, Abf, b0, rb, m, q, ks);
    if (ks2 < 3) bload(b0, WbfT, nbase, q, ks + 2);
    kstep(acc, Abf, b1, rb, m, q, ks + 1);
  }

  // ---- epilogue: tanh + v-dot, reduce over this wave's 64 cols ----
  float p[4][4];
#pragma unroll
  for (int mi = 0; mi < 4; ++mi)
#pragma unroll
    for (int j = 0; j < 4; ++j) p[mi][j] = 0.f;

#pragma unroll
  for (int nf = 0; nf < 4; ++nf) {
    const int n = wl * 64 + nf * 16 + m;
    const float vv = vvec[n];
    // C/D layout: M-coord = rb + mi*16 + 4q+j; b-index = (mi*16+4q+j)&31
    const f32x4 cvA = *(const f32x4*)(cvecT + n * NB + 4 * q);        // mi even
    const f32x4 cvB = *(const f32x4*)(cvecT + n * NB + 16 + 4 * q);   // mi odd
#pragma unroll
    for (int mi = 0; mi < 4; ++mi) {
      const f32x4 cv = (mi & 1) ? cvB : cvA;
#pragma unroll
      for (int j = 0; j < 4; ++j)
        p[mi][j] += fast_tanh(acc[mi][nf][j] + cv[j]) * vv;
    }
  }
#pragma unroll
  for (int mi = 0; mi < 4; ++mi) {
#pragma unroll
    for (int j = 0; j < 4; ++j) {
      float e = p[mi][j];
      e += __shfl_xor(e, 1, 64);
      e += __shfl_xor(e, 2, 64);
      e += __shfl_xor(e, 4, 64);
      e += __shfl_xor(e, 8, 64);  // sum over the 16 m-lanes
      if (m == 0) part[w][mi * 16 + 4 * q + j] = e;
    }
  }
  __syncthreads();
  if (tid < 128) {
    const int r = row0 + tid;  // flat row = t*NB + b
    float s = 0.f;
#pragma unroll
    for (int ww = 0; ww < 8; ++ww) s += part[(tid >> 6) * 8 + ww][tid & 63];
    scores[(r & 31) * NT + (r >> 5)] = s;
  }
}

// Fused softmax + edge scatter: one block per batch b (1024 threads).
// Softmax weights (0.1*softmax) AND the output accumulator live in LDS;
// edges do LDS atomics (ds_add_f32) instead of 262K device-scope L2 atomics;
// out is written once, coalesced (no separate zeroing pass).
__global__ __launch_bounds__(1024) void softmax_scatter(
    const float* __restrict__ sc, const int* __restrict__ esrc,
    const int* __restrict__ edst, float* __restrict__ out) {
  __shared__ float wls[NT];   // 16 KB: 0.1 * softmax(sc[b])
  __shared__ float accs[NT];  // 16 KB: scatter accumulator
  __shared__ float rtmp[16];
  __shared__ float rmax, rinv;
  const int b = blockIdx.x;
  const int tid = threadIdx.x;
  const int wid = tid >> 6, lane = tid & 63;

  float s[4];
  float mx = -1e30f;
#pragma unroll
  for (int p = 0; p < 4; ++p) {
    s[p] = sc[b * NT + tid + p * 1024];
    mx = fmaxf(mx, s[p]);
  }
#pragma unroll
  for (int d = 32; d >= 1; d >>= 1) mx = fmaxf(mx, __shfl_xor(mx, d, 64));
  if (lane == 0) rtmp[wid] = mx;
  __syncthreads();
  if (tid == 0) {
    float mm = rtmp[0];
#pragma unroll
    for (int i = 1; i < 16; ++i) mm = fmaxf(mm, rtmp[i]);
    rmax = mm;
  }
  __syncthreads();
  mx = rmax;
  float e[4];
  float sm = 0.f;
#pragma unroll
  for (int p = 0; p < 4; ++p) {
    e[p] = __expf(s[p] - mx);
    sm += e[p];
  }
#pragma unroll
  for (int d = 32; d >= 1; d >>= 1) sm += __shfl_xor(sm, d, 64);
  if (lane == 0) rtmp[wid] = sm;
  __syncthreads();
  if (tid == 0) {
    float tt = 0.f;
#pragma unroll
    for (int i = 0; i < 16; ++i) tt += rtmp[i];
    rinv = 0.1f / tt;
  }
  __syncthreads();
  const float inv = rinv;
#pragma unroll
  for (int p = 0; p < 4; ++p) {
    wls[tid + p * 1024] = e[p] * inv;
    accs[tid + p * 1024] = 0.f;
  }
  __syncthreads();
#pragma unroll
  for (int i = 0; i < 8; ++i) {
    const int eid = b * NE + tid + i * 1024;
    const int ss = esrc[eid];
    const int dd = edst[eid];
    const float wv = wls[ss];
    if (dd != ss + 1) atomicAdd(&accs[dd], wv);
  }
  __syncthreads();
#pragma unroll
  for (int p = 0; p < 4; ++p)
    out[b * NT + tid + p * 1024] = accs[tid + p * 1024];
}

extern "C" void kernel_launch(void* const* d_in, const int* in_sizes, int n_in,
                              void* d_out, int out_size, void* d_ws, size_t ws_size,
                              hipStream_t stream) {
  const float* hidden = (const float*)d_in[0];
  const float* enc    = (const float*)d_in[1];
  const int*   esrc   = (const int*)d_in[2];
  const int*   edst   = (const int*)d_in[3];
  const float* Wattn  = (const float*)d_in[4];
  const float* battn  = (const float*)d_in[5];
  const float* vvec   = (const float*)d_in[6];
  float* out = (float*)d_out;

  char* ws = (char*)d_ws;
  float* cvecT  = (float*)ws;                    // 512*32*4   = 64 KB
  short* WbfT   = (short*)(ws + 65536);          // 512*256*2  = 256 KB
  float* scores = (float*)(ws + 65536 + 262144); // 32*4096*4  = 512 KB

  prep<<<384, 256, 0, stream>>>(hidden, Wattn, battn, cvecT, WbfT);
  score_gemm<<<(NB * NT) / 128, 1024, 0, stream>>>(enc, WbfT, cvecT, vvec, scores);
  softmax_scatter<<<NB, 1024, 0, stream>>>(scores, esrc, edst, out);
}